// Round 9
// baseline (356.347 us; speedup 1.0000x reference)
//
#include <hip/hip_runtime.h>
#include <hip/hip_bf16.h>

// B=4, L=2048, D=1024, H=16, DH=64.  out = proj( softmax(QK^T/8) V ), fused QKV.
// Inputs fp32 (runtime-detected), compute bf16 MFMA, output dtype follows input.
// R17: cvt3 + QKV-GEMM fused into ONE 512-block kernel with a manual grid
//      barrier (sanctioned: __launch_bounds__(256,2) + grid=2x256 co-resident;
//      device-scope atomic + acquire spin; counter hipMemsetAsync-zeroed per
//      replay; __threadfence pre-barrier drains vmcnt so phase-2's counted
//      vmcnt(4) bookkeeping stays exact). Purpose: (1) one less launch
//      boundary; (2) ATTRIBUTION — if gemm0+cvt >= attn(93us) the fused
//      dispatch enters the top-5 with full counters; absence bounds it <93.
//      detect_bf16 -> wave-parallel ballot (same 64-sample decision, ~6 instr
//      vs ~350/wave). Phase-2 = R16-verified persistent gemm (bit-identical
//      accumulation). attn = R10-exact. proj = R16-verified ptile (tb=1).

typedef __bf16  bf16x8  __attribute__((ext_vector_type(8)));
typedef __bf16  bf16x4  __attribute__((ext_vector_type(4)));
typedef float   floatx4 __attribute__((ext_vector_type(4)));

__device__ __forceinline__ void async_ld16(const void* g, void* lds_base_uniform) {
  __builtin_amdgcn_global_load_lds(
      (const __attribute__((address_space(1))) void*)g,
      (__attribute__((address_space(3))) void*)lds_base_uniform,
      16, 0, 0);
}

// bf16-vs-fp32 probe, wave-parallel: lane i checks u16[2i] (same 64 samples
// and >=32 threshold as the original serial loop -> identical decision).
__device__ __forceinline__ int detect_bf16_wave(const void* p) {
  const unsigned short* u = (const unsigned short*)p;
  const int lane = threadIdx.x & 63;
  const unsigned short w = u[2 * lane];
  const int e = (w >> 7) & 0xFF;
  const int sane = (w == 0 || (e >= 100 && e <= 150)) ? 1 : 0;
  return __popcll(__ballot(sane)) >= 32;
}

__device__ __forceinline__ bf16x8 ld8_f32cvt(const void* base, size_t elem) {
  const float* p = (const float*)base + elem;
  floatx4 u0 = *(const floatx4*)p;
  floatx4 u1 = *(const floatx4*)(p + 4);
  bf16x8 v;
  v[0] = (__bf16)u0[0]; v[1] = (__bf16)u0[1]; v[2] = (__bf16)u0[2]; v[3] = (__bf16)u0[3];
  v[4] = (__bf16)u1[0]; v[5] = (__bf16)u1[1]; v[6] = (__bf16)u1[2]; v[7] = (__bf16)u1[3];
  return v;
}

// DPP cross-lane sum within 16-lane rows (verified R4-R7).
template<int CTRL>
__device__ __forceinline__ float dpp_f(float x) {
  return __builtin_bit_cast(float,
      __builtin_amdgcn_update_dpp(0, __builtin_bit_cast(int, x), CTRL, 0xF, 0xF, true));
}
__device__ __forceinline__ float row16_sum(float x) {
  x += dpp_f<0xB1>(x);
  x += dpp_f<0x4E>(x);
  x += dpp_f<0x141>(x);
  x += dpp_f<0x140>(x);
  return x;
}

// Manual grid barrier for a co-resident 512-block grid. ctr is zeroed by
// hipMemsetAsync before the kernel each replay. __threadfence (pre-barrier)
// makes phase-1 writes device-visible AND drains this thread's vmcnt.
__device__ __forceinline__ void grid_barrier(unsigned int* ctr, unsigned int nblk) {
  __threadfence();
  __syncthreads();
  if (threadIdx.x == 0) {
    __hip_atomic_fetch_add(ctr, 1u, __ATOMIC_ACQ_REL, __HIP_MEMORY_SCOPE_AGENT);
    while (__hip_atomic_load(ctr, __ATOMIC_ACQUIRE, __HIP_MEMORY_SCOPE_AGENT) < nblk)
      __builtin_amdgcn_s_sleep(8);
  }
  __syncthreads();
}

// ---------------------------------------------------------------------------
// fused_cvt_qkv: phase 1 = dtype-normalizing copy of x/wqkv/wproj (grid-stride,
// 12 exact iters); grid barrier; phase 2 = persistent QKV GEMM (R16-verified):
// C[8192,3072] = xb * wqkvb^T scattered to Q/K [BH,L,DH] + VT [BH,DH,L].
// 512 blocks, 2/CU. Block bx owns tiles {bx, bx+512, bx+1024} (m97 decode ->
// shared m-slab). Counted pipeline: 4-deep LDS ring, vmcnt(4) at step head
// (never 0 mid-kernel), ONE s_barrier per step; STAGE(s+2) after the barrier
// (its ring slot was last read at s-2, two barriers prior). Both-sides XOR
// swizzle: stage logical col chunk (tid&3)^((tid>>3)&3); read phys chunk
// quad^((l16>>1)&3). Accumulation order identical to R2 => bit-identical.
// ---------------------------------------------------------------------------
__launch_bounds__(256, 2)
__global__ void fused_cvt_qkv_kernel(const void* __restrict__ x,
                                     const void* __restrict__ wqkv,
                                     const void* __restrict__ wproj,
                                     __bf16* __restrict__ xb,
                                     __bf16* __restrict__ wqkvb,
                                     __bf16* __restrict__ wprojb,
                                     __bf16* __restrict__ qb,
                                     __bf16* __restrict__ kb,
                                     __bf16* __restrict__ vtb,
                                     unsigned int* __restrict__ ctr)
{
  __shared__ __align__(16) __bf16 SM[4 * 8192];   // ring buf b: A @ b*8192, B @ +4096 (elems)

  const int tid = threadIdx.x;
  const int bx  = blockIdx.x;           // 512

  // ---- phase 1: cvt (1,572,864 chunks of 8 elems; 131072 threads x 12) ----
  {
    const int u0 = bx * 256 + tid;
    for (int it = 0; it < 12; ++it) {
      int u = u0 + it * (512 * 256);
      const void* src; __bf16* dst;
      if (u < 1048576)      { src = x;     dst = xb; }
      else if (u < 1441792) { src = wqkv;  dst = wqkvb;  u -= 1048576; }
      else                  { src = wproj; dst = wprojb; u -= 1441792; }
      const int is_bf16 = detect_bf16_wave(src);
      const size_t e = (size_t)u * 8;
      if (is_bf16) *(bf16x8*)(dst + e) = *(const bf16x8*)((const __bf16*)src + e);
      else         *(bf16x8*)(dst + e) = ld8_f32cvt(src, e);
    }
  }

  grid_barrier(ctr, 512);   // all conversions visible; vmcnt drained

  // ---- phase 2: persistent QKV GEMM (R16-verified body, tb=3) ----
  const int wave = tid >> 6;
  const int lane = tid & 63;
  const int quad = lane >> 4;
  const int l16  = lane & 15;
  const int wm   = wave >> 1;
  const int wn   = wave & 1;

  const int srow = tid >> 2;            // 0..63
  const int scc  = (((tid & 3) ^ ((tid >> 3) & 3)) << 3);

  auto DECODE_M = [&](int t) { return (((t & 7) << 3) | ((t >> 3) & 7)) << 7; };
  auto DECODE_N = [&](int t) { return (t >> 6) << 7; };

  const __bf16* A = xb;
  const __bf16* B = wqkvb;

  auto STAGE = [&](int s) {
    const int t  = bx + ((s >> 5) << 9);
    const int m0 = DECODE_M(t);
    const int n0 = DECODE_N(t);
    const int k0 = (s & 31) << 5;
    char* base = (char*)SM + (s & 3) * 16384;
#pragma unroll
    for (int i = 0; i < 2; ++i) {
      async_ld16(A + (size_t)(m0 + i * 64 + srow) * 1024 + k0 + scc,
                 base + i * 4096 + wave * 1024);
      async_ld16(B + (size_t)(n0 + i * 64 + srow) * 1024 + k0 + scc,
                 base + 8192 + i * 4096 + wave * 1024);
    }
  };

  const int cswz = quad ^ ((l16 >> 1) & 3);   // phys chunk for frag reads

  floatx4 acc[4][4];
#pragma unroll
  for (int i = 0; i < 4; ++i)
#pragma unroll
    for (int j = 0; j < 4; ++j) acc[i][j] = (floatx4){0.f, 0.f, 0.f, 0.f};

  STAGE(0);
  STAGE(1);

  for (int s = 0; s < 96; ++s) {
    if (s < 95) asm volatile("s_waitcnt vmcnt(4)" ::: "memory");
    else        asm volatile("s_waitcnt vmcnt(0)" ::: "memory");
    __builtin_amdgcn_s_barrier();
    asm volatile("" ::: "memory");

    if (s + 2 < 96) STAGE(s + 2);

    const __bf16* As_ = SM + (s & 3) * 8192;
    const __bf16* Bs_ = As_ + 4096;

    bf16x8 af[4], bfr[4];
#pragma unroll
    for (int tt = 0; tt < 4; ++tt) {
      af[tt]  = *(const bf16x8*)&As_[(wm * 64 + tt * 16 + l16) * 32 + cswz * 8];
      bfr[tt] = *(const bf16x8*)&Bs_[(wn * 64 + tt * 16 + l16) * 32 + cswz * 8];
    }
    __builtin_amdgcn_s_setprio(1);
#pragma unroll
    for (int mt = 0; mt < 4; ++mt)
#pragma unroll
      for (int nt = 0; nt < 4; ++nt)
        acc[mt][nt] = __builtin_amdgcn_mfma_f32_16x16x32_bf16(af[mt], bfr[nt], acc[mt][nt], 0, 0, 0);
    __builtin_amdgcn_s_setprio(0);

    if ((s & 31) == 31) {
      // epilogue for tile s>>5 (overlaps next tile's in-flight prefetch)
      const int t  = bx + ((s >> 5) << 9);
      const int m0 = DECODE_M(t);
      const int n0 = DECODE_N(t);
      // C/D layout: col = lane&15, row = quad*4 + reg
#pragma unroll
      for (int mt = 0; mt < 4; ++mt) {
#pragma unroll
        for (int nt = 0; nt < 4; ++nt) {
          const int n_idx = n0 + wn * 64 + nt * 16 + l16;
          const int mbase = m0 + wm * 64 + mt * 16 + quad * 4;
          const int sel = n_idx >> 10;        // 0=Q 1=K 2=V (uniform per block)
          const int rem = n_idx & 1023;
          const int h   = rem >> 6;
          const int dh  = rem & 63;
          const int b   = mbase >> 11;        // same for r=0..3
          const int l   = mbase & 2047;
          const int bh  = b * 16 + h;
          if (sel == 2) {
            bf16x4 pk;
#pragma unroll
            for (int r = 0; r < 4; ++r) pk[r] = (__bf16)acc[mt][nt][r];
            *(bf16x4*)&vtb[((size_t)bh * 64 + dh) * 2048 + l] = pk;
          } else {
            __bf16* dstb = (sel == 0 ? qb : kb) + ((size_t)bh * 2048 + l) * 64 + dh;
#pragma unroll
            for (int r = 0; r < 4; ++r)
              dstb[(size_t)r * 64] = (__bf16)acc[mt][nt][r];
          }
          acc[mt][nt] = (floatx4){0.f, 0.f, 0.f, 0.f};
        }
      }
    }
  }
}

// ---------------------------------------------------------------------------
// gemm_proj: C[8192,1024] = abuf * wproj^T, row-major store, dtype per probe.
// R16-verified persistent ptile body, tb=1 (512 tiles over 512 blocks).
// ---------------------------------------------------------------------------
__launch_bounds__(256, 2)
__global__ void gemm_proj_kernel(const __bf16* __restrict__ A,
                                 const __bf16* __restrict__ B,
                                 const void* __restrict__ oprobe,
                                 void* __restrict__ Cout)
{
  __shared__ __align__(16) __bf16 SM[4 * 8192];

  const int bx   = blockIdx.x;          // 512
  const int tid  = threadIdx.x;
  const int wave = tid >> 6;
  const int lane = tid & 63;
  const int quad = lane >> 4;
  const int l16  = lane & 15;
  const int wm   = wave >> 1;
  const int wn   = wave & 1;

  const int srow = tid >> 2;
  const int scc  = (((tid & 3) ^ ((tid >> 3) & 3)) << 3);

  const int m0 = (((bx & 7) << 3) | ((bx >> 3) & 7)) << 7;
  const int n0 = (bx >> 6) << 7;

  auto STAGE = [&](int s) {
    const int k0 = (s & 31) << 5;
    char* base = (char*)SM + (s & 3) * 16384;
#pragma unroll
    for (int i = 0; i < 2; ++i) {
      async_ld16(A + (size_t)(m0 + i * 64 + srow) * 1024 + k0 + scc,
                 base + i * 4096 + wave * 1024);
      async_ld16(B + (size_t)(n0 + i * 64 + srow) * 1024 + k0 + scc,
                 base + 8192 + i * 4096 + wave * 1024);
    }
  };

  const int cswz = quad ^ ((l16 >> 1) & 3);

  floatx4 acc[4][4];
#pragma unroll
  for (int i = 0; i < 4; ++i)
#pragma unroll
    for (int j = 0; j < 4; ++j) acc[i][j] = (floatx4){0.f, 0.f, 0.f, 0.f};

  STAGE(0);
  STAGE(1);

  for (int s = 0; s < 32; ++s) {
    if (s < 31) asm volatile("s_waitcnt vmcnt(4)" ::: "memory");
    else        asm volatile("s_waitcnt vmcnt(0)" ::: "memory");
    __builtin_amdgcn_s_barrier();
    asm volatile("" ::: "memory");

    if (s + 2 < 32) STAGE(s + 2);

    const __bf16* As_ = SM + (s & 3) * 8192;
    const __bf16* Bs_ = As_ + 4096;

    bf16x8 af[4], bfr[4];
#pragma unroll
    for (int tt = 0; tt < 4; ++tt) {
      af[tt]  = *(const bf16x8*)&As_[(wm * 64 + tt * 16 + l16) * 32 + cswz * 8];
      bfr[tt] = *(const bf16x8*)&Bs_[(wn * 64 + tt * 16 + l16) * 32 + cswz * 8];
    }
    __builtin_amdgcn_s_setprio(1);
#pragma unroll
    for (int mt = 0; mt < 4; ++mt)
#pragma unroll
      for (int nt = 0; nt < 4; ++nt)
        acc[mt][nt] = __builtin_amdgcn_mfma_f32_16x16x32_bf16(af[mt], bfr[nt], acc[mt][nt], 0, 0, 0);
    __builtin_amdgcn_s_setprio(0);
  }

  const int out_bf16 = detect_bf16_wave(oprobe);
#pragma unroll
  for (int mt = 0; mt < 4; ++mt) {
#pragma unroll
    for (int nt = 0; nt < 4; ++nt) {
      const int n_idx = n0 + wn * 64 + nt * 16 + l16;
      const int mbase = m0 + wm * 64 + mt * 16 + quad * 4;
      if (out_bf16) {
#pragma unroll
        for (int r = 0; r < 4; ++r)
          ((__bf16*)Cout)[(size_t)(mbase + r) * 1024 + n_idx] = (__bf16)acc[mt][nt][r];
      } else {
#pragma unroll
        for (int r = 0; r < 4; ++r)
          ((float*)Cout)[(size_t)(mbase + r) * 1024 + n_idx] = acc[mt][nt][r];
      }
    }
  }
}

// ---------------------------------------------------------------------------
// Flash attention: grid (L/128, B*H), 4 waves/block, 32 Q rows per wave.
// R10-exact (93us proven). Fixed-shift softmax p = exp(s/8 - 8); l via ones-
// column (register B-frag). S^T = K Q^T; P LDS round-trip aliased into the
// NEXT K/V staging buffer (wave-private quarters) => ONE __syncthreads/K-tile.
// ---------------------------------------------------------------------------
__launch_bounds__(256, 4)
__global__ void attn_kernel(const __bf16* __restrict__ qb,
                            const __bf16* __restrict__ kb,
                            const __bf16* __restrict__ vtb,
                            __bf16* __restrict__ ob /* [B,L,D] bf16 */)
{
  __shared__ __align__(16) __bf16 S[2][2 * 64 * 72];

  const int tid  = threadIdx.x;
  const int wave = tid >> 6;
  const int lane = tid & 63;
  const int quad = lane >> 4;
  const int l16  = lane & 15;

  const int bh = blockIdx.y;
  const int b  = bh >> 4;
  const int h  = bh & 15;
  const int q0 = blockIdx.x * 128;

  const __bf16* Qp = qb  + (size_t)bh * 2048 * 64;
  const __bf16* Kp = kb  + (size_t)bh * 2048 * 64;
  const __bf16* Vp = vtb + (size_t)bh * 64 * 2048;

  const float C1 = 0.125f * 1.44269504f;
  const float C2 = -8.0f  * 1.44269504f;

  bf16x8 aq[2][2];
#pragma unroll
  for (int rt = 0; rt < 2; ++rt) {
    const __bf16* qrow = Qp + (size_t)(q0 + wave * 32 + rt * 16 + l16) * 64;
    aq[rt][0] = *(const bf16x8*)(qrow + quad * 8);
    aq[rt][1] = *(const bf16x8*)(qrow + 32 + quad * 8);
  }

  bf16x8 onesb;
  {
    const __bf16 ov = (l16 == 0) ? (__bf16)1.0f : (__bf16)0.0f;
#pragma unroll
    for (int i = 0; i < 8; ++i) onesb[i] = ov;
  }

  floatx4 o[2][4], o5[2];
#pragma unroll
  for (int rt = 0; rt < 2; ++rt) {
    o5[rt] = (floatx4){0.f, 0.f, 0.f, 0.f};
#pragma unroll
    for (int dt = 0; dt < 4; ++dt) o[rt][dt] = (floatx4){0.f, 0.f, 0.f, 0.f};
  }

  const int sarr = wave >> 1;
  const int srb  = (wave & 1) * 32;
  const int sr0  = lane >> 3;
  const int scol = (lane & 7) * 8;

  {
    __bf16* dst = &S[0][sarr * (64 * 72)];
    if (sarr == 0) {
#pragma unroll
      for (int i = 0; i < 4; ++i) {
        const int row = srb + sr0 + 8 * i;
        *(bf16x8*)&dst[row * 72 + scol] = *(const bf16x8*)(Kp + (size_t)row * 64 + scol);
      }
    } else {
#pragma unroll
      for (int i = 0; i < 4; ++i) {
        const int row = srb + sr0 + 8 * i;
        *(bf16x8*)&dst[row * 72 + scol] = *(const bf16x8*)(Vp + (size_t)row * 2048 + scol);
      }
    }
  }
  __syncthreads();

  for (int kt = 0; kt < 32; ++kt) {
    const int cur = kt & 1;
    const int nxt = cur ^ 1;
    const int kn  = (((kt + 1) & 31) << 6);

    bf16x8 sreg[4];
    if (sarr == 0) {
#pragma unroll
      for (int i = 0; i < 4; ++i) {
        const int row = srb + sr0 + 8 * i;
        sreg[i] = *(const bf16x8*)(Kp + (size_t)(kn + row) * 64 + scol);
      }
    } else {
#pragma unroll
      for (int i = 0; i < 4; ++i) {
        const int row = srb + sr0 + 8 * i;
        sreg[i] = *(const bf16x8*)(Vp + (size_t)row * 2048 + kn + scol);
      }
    }

    const __bf16* Kc = &S[cur][0];
    const __bf16* Vc = &S[cur][64 * 72];
    __bf16*       Pq = &S[nxt][0] + wave * 2304;

    floatx4 st[2][4];
    __builtin_amdgcn_s_setprio(1);
#pragma unroll
    for (int nt = 0; nt < 4; ++nt) {
      const int krow = nt * 16 + l16;
      bf16x8 ak0 = *(const bf16x8*)&Kc[krow * 72 + quad * 8];
      bf16x8 ak1 = *(const bf16x8*)&Kc[krow * 72 + 32 + quad * 8];
#pragma unroll
      for (int rt = 0; rt < 2; ++rt) {
        floatx4 z = (floatx4){0.f, 0.f, 0.f, 0.f};
        z = __builtin_amdgcn_mfma_f32_16x16x32_bf16(ak0, aq[rt][0], z, 0, 0, 0);
        z = __builtin_amdgcn_mfma_f32_16x16x32_bf16(ak1, aq[rt][1], z, 0, 0, 0);
        st[rt][nt] = z;
      }
    }
    __builtin_amdgcn_s_setprio(0);

#pragma unroll
    for (int rt = 0; rt < 2; ++rt) {
#pragma unroll
      for (int nt = 0; nt < 4; ++nt) {
        bf16x4 pk;
#pragma unroll
        for (int r = 0; r < 4; ++r)
          pk[r] = (__bf16)__builtin_amdgcn_exp2f(fmaf(st[rt][nt][r], C1, C2));
        *(bf16x4*)&Pq[(rt * 16 + l16) * 72 + nt * 16 + quad * 4] = pk;
      }
    }

    __builtin_amdgcn_wave_barrier();

    bf16x8 ap[2][2];
#pragma unroll
    for (int rt = 0; rt < 2; ++rt) {
      ap[rt][0] = *(const bf16x8*)&Pq[(rt * 16 + l16) * 72 + quad * 8];
      ap[rt][1] = *(const bf16x8*)&Pq[(rt * 16 + l16) * 72 + 32 + quad * 8];
    }

    __builtin_amdgcn_s_setprio(1);
#pragma unroll
    for (int dt = 0; dt < 4; ++dt) {
      const int vrow = dt * 16 + l16;
      bf16x8 bv0 = *(const bf16x8*)&Vc[vrow * 72 + quad * 8];
      bf16x8 bv1 = *(const bf16x8*)&Vc[vrow * 72 + 32 + quad * 8];
#pragma unroll
      for (int rt = 0; rt < 2; ++rt) {
        o[rt][dt] = __builtin_amdgcn_mfma_f32_16x16x32_bf16(ap[rt][0], bv0, o[rt][dt], 0, 0, 0);
        o[rt][dt] = __builtin_amdgcn_mfma_f32_16x16x32_bf16(ap[rt][1], bv1, o[rt][dt], 0, 0, 0);
      }
    }
#pragma unroll
    for (int rt = 0; rt < 2; ++rt) {
      o5[rt] = __builtin_amdgcn_mfma_f32_16x16x32_bf16(ap[rt][0], onesb, o5[rt], 0, 0, 0);
      o5[rt] = __builtin_amdgcn_mfma_f32_16x16x32_bf16(ap[rt][1], onesb, o5[rt], 0, 0, 0);
    }
    __builtin_amdgcn_s_setprio(0);

    __builtin_amdgcn_wave_barrier();

    {
      __bf16* dst = &S[nxt][sarr * (64 * 72)];
#pragma unroll
      for (int i = 0; i < 4; ++i) {
        const int row = srb + sr0 + 8 * i;
        *(bf16x8*)&dst[row * 72 + scol] = sreg[i];
      }
    }
    __syncthreads();
  }

#pragma unroll
  for (int rt = 0; rt < 2; ++rt)
#pragma unroll
    for (int r = 0; r < 4; ++r) {
      const float lv  = row16_sum(l16 == 0 ? o5[rt][r] : 0.f);
      const float inv = 1.f / lv;
      const size_t rowbase =
          ((size_t)b * 2048 + q0 + wave * 32 + rt * 16 + quad * 4 + r) * 1024 + h * 64;
#pragma unroll
      for (int dt = 0; dt < 4; ++dt)
        ob[rowbase + dt * 16 + l16] = (__bf16)(o[rt][dt][r] * inv);
    }
}

// ---------------------------------------------------------------------------
extern "C" void kernel_launch(void* const* d_in, const int* in_sizes, int n_in,
                              void* d_out, int out_size, void* d_ws, size_t ws_size,
                              hipStream_t stream)
{
  (void)in_sizes; (void)n_in; (void)out_size; (void)ws_size;

  const void* x     = d_in[0];
  const void* wqkv  = d_in[1];
  const void* wproj = d_in[2];

  const size_t NX    = (size_t)8192 * 1024;
  const size_t NWQKV = (size_t)3072 * 1024;
  const size_t NWPRJ = (size_t)1024 * 1024;

  __bf16* qbuf   = (__bf16*)d_ws;
  __bf16* kbuf   = qbuf + NX;
  __bf16* vtbuf  = kbuf + NX;
  __bf16* abuf   = vtbuf + NX;
  __bf16* xb     = abuf + NX;
  __bf16* wqkvb  = xb + NX;
  __bf16* wprojb = wqkvb + NWQKV;
  unsigned int* ctr = (unsigned int*)(wprojb + NWPRJ);

  dim3 blk(256);

  hipMemsetAsync(ctr, 0, 64, stream);

  fused_cvt_qkv_kernel<<<dim3(512), blk, 0, stream>>>(
      x, wqkv, wproj, xb, wqkvb, wprojb, qbuf, kbuf, vtbuf, ctr);

  attn_kernel<<<dim3(2048 / 128, 64), blk, 0, stream>>>(qbuf, kbuf, vtbuf, abuf);

  gemm_proj_kernel<<<dim3(512), blk, 0, stream>>>(abuf, wprojb, wproj, d_out);
}

// Round 10
// 268.008 us; speedup vs baseline: 1.3296x; 1.3296x over previous
//
#include <hip/hip_runtime.h>
#include <hip/hip_bf16.h>

// B=4, L=2048, D=1024, H=16, DH=64.  out = proj( softmax(QK^T/8) V ), fused QKV.
// Inputs fp32 (runtime-detected), compute bf16 MFMA, output dtype follows input.
// R18: R17 fusion reverted (post-mortem: BW-bound cvt phase under the GEMM's
//      2-blocks/CU occupancy ran at 786 GB/s => ~90us; never fuse streaming
//      phases into LDS-heavy kernels). gemm0 rebuilt at the HK design point:
//      BM=256xBN=128, BK=64, 8 waves (512 thr), 3-slot LDS ring (144 KB,
//      1 block/CU), 4 phases/K-tile each {ds_read frags; issue 2 stage loads;
//      lgkmcnt(0); setprio(1); 8 MFMA; setprio(0); s_barrier}. Counted
//      vmcnt(6) once per K-tile (drain only at the last). WAR on the ring is
//      barrier-proven: slot kt%3 rewritten during kt+1, after the kt+1-P0
//      barrier which orders every wave's lgkm-complete kt reads. chunk-XOR
//      swizzle phys=log^(row&7) (R17: measured ZERO bank conflicts family);
//      LDS dest linear so global_load_lds legal. k ascending per element =>
//      bit-identical output. Grid 768 = 8 XCD x (4m x 24n), 3 exact rounds.
//      attn = R10-exact. proj = R17-verified gemm_proj. cvt3 = ballot detect.

typedef __bf16  bf16x8  __attribute__((ext_vector_type(8)));
typedef __bf16  bf16x4  __attribute__((ext_vector_type(4)));
typedef float   floatx4 __attribute__((ext_vector_type(4)));

__device__ __forceinline__ void async_ld16(const void* g, void* lds_base_uniform) {
  __builtin_amdgcn_global_load_lds(
      (const __attribute__((address_space(1))) void*)g,
      (__attribute__((address_space(3))) void*)lds_base_uniform,
      16, 0, 0);
}

// bf16-vs-fp32 probe, wave-parallel ballot (verified R17): lane i checks
// u16[2i] — same 64 samples and >=32 threshold as the original serial probe.
__device__ __forceinline__ int detect_bf16_wave(const void* p) {
  const unsigned short* u = (const unsigned short*)p;
  const int lane = threadIdx.x & 63;
  const unsigned short w = u[2 * lane];
  const int e = (w >> 7) & 0xFF;
  const int sane = (w == 0 || (e >= 100 && e <= 150)) ? 1 : 0;
  return __popcll(__ballot(sane)) >= 32;
}

__device__ __forceinline__ bf16x8 ld8_f32cvt(const void* base, size_t elem) {
  const float* p = (const float*)base + elem;
  floatx4 u0 = *(const floatx4*)p;
  floatx4 u1 = *(const floatx4*)(p + 4);
  bf16x8 v;
  v[0] = (__bf16)u0[0]; v[1] = (__bf16)u0[1]; v[2] = (__bf16)u0[2]; v[3] = (__bf16)u0[3];
  v[4] = (__bf16)u1[0]; v[5] = (__bf16)u1[1]; v[6] = (__bf16)u1[2]; v[7] = (__bf16)u1[3];
  return v;
}

// DPP cross-lane sum within 16-lane rows (verified R4-R7).
template<int CTRL>
__device__ __forceinline__ float dpp_f(float x) {
  return __builtin_bit_cast(float,
      __builtin_amdgcn_update_dpp(0, __builtin_bit_cast(int, x), CTRL, 0xF, 0xF, true));
}
__device__ __forceinline__ float row16_sum(float x) {
  x += dpp_f<0xB1>(x);
  x += dpp_f<0x4E>(x);
  x += dpp_f<0x141>(x);
  x += dpp_f<0x140>(x);
  return x;
}

// ---------------------------------------------------------------------------
// fused dtype-normalizing copy over 3 segments (segment starts block-aligned)
// ---------------------------------------------------------------------------
__launch_bounds__(256)
__global__ void cvt3_kernel(const void* __restrict__ s0, __bf16* __restrict__ d0, int n0,
                            const void* __restrict__ s1, __bf16* __restrict__ d1, int n1,
                            const void* __restrict__ s2, __bf16* __restrict__ d2) {
  int u = blockIdx.x * blockDim.x + threadIdx.x;
  const void* src; __bf16* dst;
  if (u < n0)           { src = s0; dst = d0; }
  else if (u < n0 + n1) { src = s1; dst = d1; u -= n0; }
  else                  { src = s2; dst = d2; u -= n0 + n1; }
  const int is_bf16 = detect_bf16_wave(src);
  const size_t e = (size_t)u * 8;
  if (is_bf16) *(bf16x8*)(dst + e) = *(const bf16x8*)((const __bf16*)src + e);
  else         *(bf16x8*)(dst + e) = ld8_f32cvt(src, e);
}

// ---------------------------------------------------------------------------
// gemm_qkv8: C[8192,3072] = X * Wqkv^T scattered to Q/K [BH,L,DH] + VT.
// BM=256 BN=128 BK=64, 8 waves (wm=wave>>1 in 0..3 rows, wn=wave&1 cols).
// 3-slot LDS ring (slot = A 256x64 | B 128x64 = 48 KB); stage lead = 2 K-tiles.
// Per K-tile: 4 phases (see header comment). vmcnt(6) at K-tile head only.
// Swizzle: stage thread slot s: row=s>>3, phys chunk=s&7, global col chunk =
// (s&7)^(row&7); LDS byte = slotBase + s*16 (linear). Read: phys =
// (ks*4+quad)^(row&7). 2 lanes/bank => conflict-free (R17-verified family).
// ---------------------------------------------------------------------------
__launch_bounds__(512, 1)
__global__ void gemm_qkv8_kernel(const __bf16* __restrict__ A,
                                 const __bf16* __restrict__ B,
                                 __bf16* __restrict__ qb,
                                 __bf16* __restrict__ kb,
                                 __bf16* __restrict__ vtb)
{
  __shared__ __align__(16) __bf16 SM[3 * 24576];   // 144 KB

  const int flat = blockIdx.x;          // 768 = 8 XCD x (4 m x 24 n), bijective
  const int xcd  = flat & 7;
  const int j    = flat >> 3;           // 0..95
  const int m0   = ((xcd << 2) | (j & 3)) << 8;
  const int n0   = (j >> 2) << 7;

  const int tid  = threadIdx.x;
  const int wave = tid >> 6;            // 0..7
  const int lane = tid & 63;
  const int quad = lane >> 4;
  const int l16  = lane & 15;
  const int wm   = wave >> 1;           // 0..3 (64-row band)
  const int wn   = wave & 1;            // 0..1 (64-col band)

  auto STAGE_A = [&](int kt2, int a) {  // a = 0..3 (2 issued per phase)
    const int s   = a * 512 + tid;      // 0..2047
    const int row = s >> 3;             // 0..255
    const int col = ((s & 7) ^ (row & 7)) << 3;
    async_ld16(A + (size_t)(m0 + row) * 1024 + (kt2 << 6) + col,
               (char*)SM + (kt2 % 3) * 49152 + (a * 512 + wave * 64) * 16);
  };
  auto STAGE_B = [&](int kt2, int b) {  // b = 0..1
    const int s   = b * 512 + tid;      // 0..1023
    const int row = s >> 3;             // 0..127
    const int col = ((s & 7) ^ (row & 7)) << 3;
    async_ld16(B + (size_t)(n0 + row) * 1024 + (kt2 << 6) + col,
               (char*)SM + (kt2 % 3) * 49152 + 32768 + (b * 512 + wave * 64) * 16);
  };

  floatx4 acc[4][4];
#pragma unroll
  for (int i = 0; i < 4; ++i)
#pragma unroll
    for (int nf = 0; nf < 4; ++nf) acc[i][nf] = (floatx4){0.f, 0.f, 0.f, 0.f};

  // prologue: stage K-tiles 0 and 1 (6 loads each, in-order groups)
#pragma unroll
  for (int a = 0; a < 4; ++a) STAGE_A(0, a);
#pragma unroll
  for (int b = 0; b < 2; ++b) STAGE_B(0, b);
#pragma unroll
  for (int a = 0; a < 4; ++a) STAGE_A(1, a);
#pragma unroll
  for (int b = 0; b < 2; ++b) STAGE_B(1, b);

  for (int kt = 0; kt < 16; ++kt) {
    const __bf16* SL = SM + (kt % 3) * 24576;
    const int go = (kt < 14);

    auto RA = [&](int mf, int ks) {
      const int row = wm * 64 + mf * 16 + l16;
      return *(const bf16x8*)&SL[row * 64 + (((ks << 2) | quad) ^ (row & 7)) * 8];
    };
    auto RB = [&](int nf, int ks) {
      const int row = wn * 64 + nf * 16 + l16;
      return *(const bf16x8*)&SL[16384 + row * 64 + (((ks << 2) | quad) ^ (row & 7)) * 8];
    };

    // ---- P0: slot ready (counted); A ks0 + B0,B1 ks0; stage A0,A1 of kt+2
    if (kt < 15) asm volatile("s_waitcnt vmcnt(6)" ::: "memory");
    else         asm volatile("s_waitcnt vmcnt(0)" ::: "memory");
    __builtin_amdgcn_s_barrier();
    asm volatile("" ::: "memory");

    bf16x8 a0[4];
#pragma unroll
    for (int mf = 0; mf < 4; ++mf) a0[mf] = RA(mf, 0);
    bf16x8 b00 = RB(0, 0), b10 = RB(1, 0);
    if (go) { STAGE_A(kt + 2, 0); STAGE_A(kt + 2, 1); }
    asm volatile("s_waitcnt lgkmcnt(0)" ::: "memory");
    __builtin_amdgcn_sched_barrier(0);
    __builtin_amdgcn_s_setprio(1);
#pragma unroll
    for (int mf = 0; mf < 4; ++mf) {
      acc[mf][0] = __builtin_amdgcn_mfma_f32_16x16x32_bf16(a0[mf], b00, acc[mf][0], 0, 0, 0);
      acc[mf][1] = __builtin_amdgcn_mfma_f32_16x16x32_bf16(a0[mf], b10, acc[mf][1], 0, 0, 0);
    }
    __builtin_amdgcn_s_setprio(0);
    __builtin_amdgcn_s_barrier();
    asm volatile("" ::: "memory");

    // ---- P1: B2,B3 ks0; stage A2,A3
    bf16x8 b20 = RB(2, 0), b30 = RB(3, 0);
    if (go) { STAGE_A(kt + 2, 2); STAGE_A(kt + 2, 3); }
    asm volatile("s_waitcnt lgkmcnt(0)" ::: "memory");
    __builtin_amdgcn_sched_barrier(0);
    __builtin_amdgcn_s_setprio(1);
#pragma unroll
    for (int mf = 0; mf < 4; ++mf) {
      acc[mf][2] = __builtin_amdgcn_mfma_f32_16x16x32_bf16(a0[mf], b20, acc[mf][2], 0, 0, 0);
      acc[mf][3] = __builtin_amdgcn_mfma_f32_16x16x32_bf16(a0[mf], b30, acc[mf][3], 0, 0, 0);
    }
    __builtin_amdgcn_s_setprio(0);
    __builtin_amdgcn_s_barrier();
    asm volatile("" ::: "memory");

    // ---- P2: A ks1 + B0,B1 ks1; stage B0,B1
    bf16x8 a1[4];
#pragma unroll
    for (int mf = 0; mf < 4; ++mf) a1[mf] = RA(mf, 1);
    bf16x8 b01 = RB(0, 1), b11 = RB(1, 1);
    if (go) { STAGE_B(kt + 2, 0); STAGE_B(kt + 2, 1); }
    asm volatile("s_waitcnt lgkmcnt(0)" ::: "memory");
    __builtin_amdgcn_sched_barrier(0);
    __builtin_amdgcn_s_setprio(1);
#pragma unroll
    for (int mf = 0; mf < 4; ++mf) {
      acc[mf][0] = __builtin_amdgcn_mfma_f32_16x16x32_bf16(a1[mf], b01, acc[mf][0], 0, 0, 0);
      acc[mf][1] = __builtin_amdgcn_mfma_f32_16x16x32_bf16(a1[mf], b11, acc[mf][1], 0, 0, 0);
    }
    __builtin_amdgcn_s_setprio(0);
    __builtin_amdgcn_s_barrier();
    asm volatile("" ::: "memory");

    // ---- P3: B2,B3 ks1 (next K-tile's P0 provides the trailing barrier)
    bf16x8 b21 = RB(2, 1), b31 = RB(3, 1);
    asm volatile("s_waitcnt lgkmcnt(0)" ::: "memory");
    __builtin_amdgcn_sched_barrier(0);
    __builtin_amdgcn_s_setprio(1);
#pragma unroll
    for (int mf = 0; mf < 4; ++mf) {
      acc[mf][2] = __builtin_amdgcn_mfma_f32_16x16x32_bf16(a1[mf], b21, acc[mf][2], 0, 0, 0);
      acc[mf][3] = __builtin_amdgcn_mfma_f32_16x16x32_bf16(a1[mf], b31, acc[mf][3], 0, 0, 0);
    }
    __builtin_amdgcn_s_setprio(0);
  }

  // scatter epilogue (same math as R2 EPI=0; C/D: col=lane&15, row=quad*4+reg)
#pragma unroll
  for (int mf = 0; mf < 4; ++mf) {
#pragma unroll
    for (int nf = 0; nf < 4; ++nf) {
      const int n_idx = n0 + wn * 64 + nf * 16 + l16;
      const int mbase = m0 + wm * 64 + mf * 16 + quad * 4;
      const int sel = n_idx >> 10;        // 0=Q 1=K 2=V (BN=128 never straddles)
      const int rem = n_idx & 1023;
      const int h   = rem >> 6;
      const int dh  = rem & 63;
      const int b   = mbase >> 11;        // same for r=0..3 (mbase % 4 == 0)
      const int l   = mbase & 2047;
      const int bh  = b * 16 + h;
      if (sel == 2) {
        bf16x4 pk;
#pragma unroll
        for (int r = 0; r < 4; ++r) pk[r] = (__bf16)acc[mf][nf][r];
        *(bf16x4*)&vtb[((size_t)bh * 64 + dh) * 2048 + l] = pk;   // 4 consecutive l
      } else {
        __bf16* dstb = (sel == 0 ? qb : kb) + ((size_t)bh * 2048 + l) * 64 + dh;
#pragma unroll
        for (int r = 0; r < 4; ++r)
          dstb[(size_t)r * 64] = (__bf16)acc[mf][nf][r];
      }
    }
  }
}

// ---------------------------------------------------------------------------
// gemm_proj: C[8192,1024] = abuf * wproj^T, row-major store, dtype per probe.
// R16/R17-verified persistent ptile body (counted vmcnt(4), 4-slot ring).
// ---------------------------------------------------------------------------
__launch_bounds__(256, 2)
__global__ void gemm_proj_kernel(const __bf16* __restrict__ A,
                                 const __bf16* __restrict__ B,
                                 const void* __restrict__ oprobe,
                                 void* __restrict__ Cout)
{
  __shared__ __align__(16) __bf16 SM[4 * 8192];

  const int bx   = blockIdx.x;          // 512
  const int tid  = threadIdx.x;
  const int wave = tid >> 6;
  const int lane = tid & 63;
  const int quad = lane >> 4;
  const int l16  = lane & 15;
  const int wm   = wave >> 1;
  const int wn   = wave & 1;

  const int srow = tid >> 2;
  const int scc  = (((tid & 3) ^ ((tid >> 3) & 3)) << 3);

  const int m0 = (((bx & 7) << 3) | ((bx >> 3) & 7)) << 7;
  const int n0 = (bx >> 6) << 7;

  auto STAGE = [&](int s) {
    const int k0 = (s & 31) << 5;
    char* base = (char*)SM + (s & 3) * 16384;
#pragma unroll
    for (int i = 0; i < 2; ++i) {
      async_ld16(A + (size_t)(m0 + i * 64 + srow) * 1024 + k0 + scc,
                 base + i * 4096 + wave * 1024);
      async_ld16(B + (size_t)(n0 + i * 64 + srow) * 1024 + k0 + scc,
                 base + 8192 + i * 4096 + wave * 1024);
    }
  };

  const int cswz = quad ^ ((l16 >> 1) & 3);

  floatx4 acc[4][4];
#pragma unroll
  for (int i = 0; i < 4; ++i)
#pragma unroll
    for (int j = 0; j < 4; ++j) acc[i][j] = (floatx4){0.f, 0.f, 0.f, 0.f};

  STAGE(0);
  STAGE(1);

  for (int s = 0; s < 32; ++s) {
    if (s < 31) asm volatile("s_waitcnt vmcnt(4)" ::: "memory");
    else        asm volatile("s_waitcnt vmcnt(0)" ::: "memory");
    __builtin_amdgcn_s_barrier();
    asm volatile("" ::: "memory");

    if (s + 2 < 32) STAGE(s + 2);

    const __bf16* As_ = SM + (s & 3) * 8192;
    const __bf16* Bs_ = As_ + 4096;

    bf16x8 af[4], bfr[4];
#pragma unroll
    for (int tt = 0; tt < 4; ++tt) {
      af[tt]  = *(const bf16x8*)&As_[(wm * 64 + tt * 16 + l16) * 32 + cswz * 8];
      bfr[tt] = *(const bf16x8*)&Bs_[(wn * 64 + tt * 16 + l16) * 32 + cswz * 8];
    }
    __builtin_amdgcn_s_setprio(1);
#pragma unroll
    for (int mt = 0; mt < 4; ++mt)
#pragma unroll
      for (int nt = 0; nt < 4; ++nt)
        acc[mt][nt] = __builtin_amdgcn_mfma_f32_16x16x32_bf16(af[mt], bfr[nt], acc[mt][nt], 0, 0, 0);
    __builtin_amdgcn_s_setprio(0);
  }

  const int out_bf16 = detect_bf16_wave(oprobe);
#pragma unroll
  for (int mt = 0; mt < 4; ++mt) {
#pragma unroll
    for (int nt = 0; nt < 4; ++nt) {
      const int n_idx = n0 + wn * 64 + nt * 16 + l16;
      const int mbase = m0 + wm * 64 + mt * 16 + quad * 4;
      if (out_bf16) {
#pragma unroll
        for (int r = 0; r < 4; ++r)
          ((__bf16*)Cout)[(size_t)(mbase + r) * 1024 + n_idx] = (__bf16)acc[mt][nt][r];
      } else {
#pragma unroll
        for (int r = 0; r < 4; ++r)
          ((float*)Cout)[(size_t)(mbase + r) * 1024 + n_idx] = acc[mt][nt][r];
      }
    }
  }
}

// ---------------------------------------------------------------------------
// Flash attention: grid (L/128, B*H), 4 waves/block, 32 Q rows per wave.
// R10-exact (93us proven). Fixed-shift softmax p = exp(s/8 - 8); l via ones-
// column (register B-frag). S^T = K Q^T; P LDS round-trip aliased into the
// NEXT K/V staging buffer (wave-private quarters) => ONE __syncthreads/K-tile.
// ---------------------------------------------------------------------------
__launch_bounds__(256, 4)
__global__ void attn_kernel(const __bf16* __restrict__ qb,
                            const __bf16* __restrict__ kb,
                            const __bf16* __restrict__ vtb,
                            __bf16* __restrict__ ob /* [B,L,D] bf16 */)
{
  __shared__ __align__(16) __bf16 S[2][2 * 64 * 72];

  const int tid  = threadIdx.x;
  const int wave = tid >> 6;
  const int lane = tid & 63;
  const int quad = lane >> 4;
  const int l16  = lane & 15;

  const int bh = blockIdx.y;
  const int b  = bh >> 4;
  const int h  = bh & 15;
  const int q0 = blockIdx.x * 128;

  const __bf16* Qp = qb  + (size_t)bh * 2048 * 64;
  const __bf16* Kp = kb  + (size_t)bh * 2048 * 64;
  const __bf16* Vp = vtb + (size_t)bh * 64 * 2048;

  const float C1 = 0.125f * 1.44269504f;
  const float C2 = -8.0f  * 1.44269504f;

  bf16x8 aq[2][2];
#pragma unroll
  for (int rt = 0; rt < 2; ++rt) {
    const __bf16* qrow = Qp + (size_t)(q0 + wave * 32 + rt * 16 + l16) * 64;
    aq[rt][0] = *(const bf16x8*)(qrow + quad * 8);
    aq[rt][1] = *(const bf16x8*)(qrow + 32 + quad * 8);
  }

  bf16x8 onesb;
  {
    const __bf16 ov = (l16 == 0) ? (__bf16)1.0f : (__bf16)0.0f;
#pragma unroll
    for (int i = 0; i < 8; ++i) onesb[i] = ov;
  }

  floatx4 o[2][4], o5[2];
#pragma unroll
  for (int rt = 0; rt < 2; ++rt) {
    o5[rt] = (floatx4){0.f, 0.f, 0.f, 0.f};
#pragma unroll
    for (int dt = 0; dt < 4; ++dt) o[rt][dt] = (floatx4){0.f, 0.f, 0.f, 0.f};
  }

  const int sarr = wave >> 1;
  const int srb  = (wave & 1) * 32;
  const int sr0  = lane >> 3;
  const int scol = (lane & 7) * 8;

  {
    __bf16* dst = &S[0][sarr * (64 * 72)];
    if (sarr == 0) {
#pragma unroll
      for (int i = 0; i < 4; ++i) {
        const int row = srb + sr0 + 8 * i;
        *(bf16x8*)&dst[row * 72 + scol] = *(const bf16x8*)(Kp + (size_t)row * 64 + scol);
      }
    } else {
#pragma unroll
      for (int i = 0; i < 4; ++i) {
        const int row = srb + sr0 + 8 * i;
        *(bf16x8*)&dst[row * 72 + scol] = *(const bf16x8*)(Vp + (size_t)row * 2048 + scol);
      }
    }
  }
  __syncthreads();

  for (int kt = 0; kt < 32; ++kt) {
    const int cur = kt & 1;
    const int nxt = cur ^ 1;
    const int kn  = (((kt + 1) & 31) << 6);

    bf16x8 sreg[4];
    if (sarr == 0) {
#pragma unroll
      for (int i = 0; i < 4; ++i) {
        const int row = srb + sr0 + 8 * i;
        sreg[i] = *(const bf16x8*)(Kp + (size_t)(kn + row) * 64 + scol);
      }
    } else {
#pragma unroll
      for (int i = 0; i < 4; ++i) {
        const int row = srb + sr0 + 8 * i;
        sreg[i] = *(const bf16x8*)(Vp + (size_t)row * 2048 + kn + scol);
      }
    }

    const __bf16* Kc = &S[cur][0];
    const __bf16* Vc = &S[cur][64 * 72];
    __bf16*       Pq = &S[nxt][0] + wave * 2304;

    floatx4 st[2][4];
    __builtin_amdgcn_s_setprio(1);
#pragma unroll
    for (int nt = 0; nt < 4; ++nt) {
      const int krow = nt * 16 + l16;
      bf16x8 ak0 = *(const bf16x8*)&Kc[krow * 72 + quad * 8];
      bf16x8 ak1 = *(const bf16x8*)&Kc[krow * 72 + 32 + quad * 8];
#pragma unroll
      for (int rt = 0; rt < 2; ++rt) {
        floatx4 z = (floatx4){0.f, 0.f, 0.f, 0.f};
        z = __builtin_amdgcn_mfma_f32_16x16x32_bf16(ak0, aq[rt][0], z, 0, 0, 0);
        z = __builtin_amdgcn_mfma_f32_16x16x32_bf16(ak1, aq[rt][1], z, 0, 0, 0);
        st[rt][nt] = z;
      }
    }
    __builtin_amdgcn_s_setprio(0);

#pragma unroll
    for (int rt = 0; rt < 2; ++rt) {
#pragma unroll
      for (int nt = 0; nt < 4; ++nt) {
        bf16x4 pk;
#pragma unroll
        for (int r = 0; r < 4; ++r)
          pk[r] = (__bf16)__builtin_amdgcn_exp2f(fmaf(st[rt][nt][r], C1, C2));
        *(bf16x4*)&Pq[(rt * 16 + l16) * 72 + nt * 16 + quad * 4] = pk;
      }
    }

    __builtin_amdgcn_wave_barrier();

    bf16x8 ap[2][2];
#pragma unroll
    for (int rt = 0; rt < 2; ++rt) {
      ap[rt][0] = *(const bf16x8*)&Pq[(rt * 16 + l16) * 72 + quad * 8];
      ap[rt][1] = *(const bf16x8*)&Pq[(rt * 16 + l16) * 72 + 32 + quad * 8];
    }

    __builtin_amdgcn_s_setprio(1);
#pragma unroll
    for (int dt = 0; dt < 4; ++dt) {
      const int vrow = dt * 16 + l16;
      bf16x8 bv0 = *(const bf16x8*)&Vc[vrow * 72 + quad * 8];
      bf16x8 bv1 = *(const bf16x8*)&Vc[vrow * 72 + 32 + quad * 8];
#pragma unroll
      for (int rt = 0; rt < 2; ++rt) {
        o[rt][dt] = __builtin_amdgcn_mfma_f32_16x16x32_bf16(ap[rt][0], bv0, o[rt][dt], 0, 0, 0);
        o[rt][dt] = __builtin_amdgcn_mfma_f32_16x16x32_bf16(ap[rt][1], bv1, o[rt][dt], 0, 0, 0);
      }
    }
#pragma unroll
    for (int rt = 0; rt < 2; ++rt) {
      o5[rt] = __builtin_amdgcn_mfma_f32_16x16x32_bf16(ap[rt][0], onesb, o5[rt], 0, 0, 0);
      o5[rt] = __builtin_amdgcn_mfma_f32_16x16x32_bf16(ap[rt][1], onesb, o5[rt], 0, 0, 0);
    }
    __builtin_amdgcn_s_setprio(0);

    __builtin_amdgcn_wave_barrier();

    {
      __bf16* dst = &S[nxt][sarr * (64 * 72)];
#pragma unroll
      for (int i = 0; i < 4; ++i) {
        const int row = srb + sr0 + 8 * i;
        *(bf16x8*)&dst[row * 72 + scol] = sreg[i];
      }
    }
    __syncthreads();
  }

#pragma unroll
  for (int rt = 0; rt < 2; ++rt)
#pragma unroll
    for (int r = 0; r < 4; ++r) {
      const float lv  = row16_sum(l16 == 0 ? o5[rt][r] : 0.f);
      const float inv = 1.f / lv;
      const size_t rowbase =
          ((size_t)b * 2048 + q0 + wave * 32 + rt * 16 + quad * 4 + r) * 1024 + h * 64;
#pragma unroll
      for (int dt = 0; dt < 4; ++dt)
        ob[rowbase + dt * 16 + l16] = (__bf16)(o[rt][dt][r] * inv);
    }
}

// ---------------------------------------------------------------------------
extern "C" void kernel_launch(void* const* d_in, const int* in_sizes, int n_in,
                              void* d_out, int out_size, void* d_ws, size_t ws_size,
                              hipStream_t stream)
{
  (void)in_sizes; (void)n_in; (void)out_size; (void)ws_size;

  const void* x     = d_in[0];
  const void* wqkv  = d_in[1];
  const void* wproj = d_in[2];

  const size_t NX    = (size_t)8192 * 1024;
  const size_t NWQKV = (size_t)3072 * 1024;
  const size_t NWPRJ = (size_t)1024 * 1024;

  __bf16* qbuf   = (__bf16*)d_ws;
  __bf16* kbuf   = qbuf + NX;
  __bf16* vtbuf  = kbuf + NX;
  __bf16* abuf   = vtbuf + NX;
  __bf16* xb     = abuf + NX;
  __bf16* wqkvb  = xb + NX;
  __bf16* wprojb = wqkvb + NWQKV;

  cvt3_kernel<<<dim3((NX + NWQKV + NWPRJ) / 2048), dim3(256), 0, stream>>>(
      x, xb, NX / 8, wqkv, wqkvb, NWQKV / 8, wproj, wprojb);

  gemm_qkv8_kernel<<<dim3(768), dim3(512), 0, stream>>>(
      xb, wqkvb, qbuf, kbuf, vtbuf);

  attn_kernel<<<dim3(2048 / 128, 64), dim3(256), 0, stream>>>(qbuf, kbuf, vtbuf, abuf);

  gemm_proj_kernel<<<dim3(512), dim3(256), 0, stream>>>(abuf, wprojb, wproj, d_out);
}